// Round 1
// baseline (1032.138 us; speedup 1.0000x reference)
//
#include <hip/hip_runtime.h>
#include <math.h>

#define NB_B 32
#define NH 32
#define NKVH 8
#define GQ 4            // NH / NKVH
#define HD 128
#define BS 16
#define MAX_KV 4096
#define BPS 256         // MAX_KV / BS
#define NSPLIT 4
#define SPLIT_LEN 1024  // MAX_KV / NSPLIT
#define ATT_SCALE 0.08838834764831845f

__device__ __forceinline__ float wave_max64(float v) {
#pragma unroll
  for (int off = 32; off > 0; off >>= 1) v = fmaxf(v, __shfl_xor(v, off, 64));
  return v;
}
__device__ __forceinline__ float wave_sum64(float v) {
#pragma unroll
  for (int off = 32; off > 0; off >>= 1) v += __shfl_xor(v, off, 64);
  return v;
}

// ws layout:
//   ws_o: [B][KVH][NSPLIT][GQ][HD]  float
//   ws_m: [B][KVH][NSPLIT][GQ]      float
//   ws_l: [B][KVH][NSPLIT][GQ]      float
__launch_bounds__(256, 2)
__global__ void attn_split_kernel(const float* __restrict__ q,
                                  const float* __restrict__ kc,
                                  const float* __restrict__ vc,
                                  const int* __restrict__ seqlens,
                                  const int* __restrict__ btab,
                                  float* __restrict__ ws_o,
                                  float* __restrict__ ws_m,
                                  float* __restrict__ ws_l) {
  const int split = blockIdx.x;
  const int kvh   = blockIdx.y;
  const int b     = blockIdx.z;
  const int tid   = threadIdx.x;
  const int wave  = tid >> 6;
  const int lane  = tid & 63;

  const int seqlen = seqlens[b];
  const int start  = split * SPLIT_LEN;
  const int end    = min(seqlen, start + SPLIT_LEN);
  const int midx   = ((b * NKVH + kvh) * NSPLIT + split) * GQ;

  if (end <= start) {
    // empty split: write neutral partials (ws is poisoned before every call)
    if (tid < GQ) { ws_m[midx + tid] = -INFINITY; ws_l[midx + tid] = 0.f; }
    float* op = ws_o + (size_t)midx * HD;   // GQ*HD = 512 floats
    op[tid] = 0.f;
    op[tid + 256] = 0.f;
    return;
  }

  __shared__ float p_lds[4][GQ][64];
  __shared__ float wm[4][GQ];
  __shared__ float wl[4][GQ];
  __shared__ float wo[4][GQ][HD];

  // per-wave online softmax state
  float m_h[GQ], lpart[GQ];
  float2 o2[GQ];
#pragma unroll
  for (int h = 0; h < GQ; ++h) {
    m_h[h] = -INFINITY;
    lpart[h] = 0.f;
    o2[h] = make_float2(0.f, 0.f);
  }

  const float* qbase = q + ((size_t)b * NH + (size_t)kvh * GQ) * HD;  // qbase[h*HD + d], wave-uniform
  const int* bt = btab + (size_t)b * BPS;

#pragma unroll 1
  for (int cbase = start + wave * 64; cbase < end; cbase += 4 * 64) {
    const int tok = cbase + lane;
    // ---- phase 1: lane-per-token scores ----
    const int blk = bt[tok >> 4];  // lane-varying gather (4 distinct values/chunk)
    const float* krow = kc + (((size_t)blk * BS + (tok & 15)) * NKVH + kvh) * HD;

    float s[GQ] = {0.f, 0.f, 0.f, 0.f};
#pragma unroll
    for (int dg = 0; dg < HD; dg += 4) {
      const float4 k4 = *(const float4*)(krow + dg);
#pragma unroll
      for (int h = 0; h < GQ; ++h) {
        const float* qh = qbase + h * HD + dg;  // uniform -> s_load
        s[h] = fmaf(qh[0], k4.x, s[h]);
        s[h] = fmaf(qh[1], k4.y, s[h]);
        s[h] = fmaf(qh[2], k4.z, s[h]);
        s[h] = fmaf(qh[3], k4.w, s[h]);
      }
    }

    const bool valid = (tok < end);
#pragma unroll
    for (int h = 0; h < GQ; ++h) {
      const float sv = valid ? s[h] * ATT_SCALE : -INFINITY;
      const float mx = wave_max64(sv);           // finite: lane 0 always valid
      const float mnew = fmaxf(m_h[h], mx);
      const float alpha = __expf(m_h[h] - mnew); // uniform across wave
      const float p = __expf(sv - mnew);         // 0 for invalid lanes
      m_h[h] = mnew;
      lpart[h] = lpart[h] * alpha + p;
      o2[h].x *= alpha;
      o2[h].y *= alpha;
      p_lds[wave][h][lane] = p;
    }
    __builtin_amdgcn_wave_barrier();  // wave-synchronous: order p write vs read

    // ---- phase 2: lane-per-d-pair PV accumulate ----
#pragma unroll
    for (int blk4 = 0; blk4 < 4; ++blk4) {          // 4 cache blocks per 64-token chunk
      const int t0 = cbase + blk4 * 16;
      const int pblk = bt[t0 >> 4];                 // uniform -> s_load
      const float* vbase = vc + ((size_t)pblk * BS * NKVH + kvh) * HD;
#pragma unroll
      for (int tt = 0; tt < 16; tt += 4) {
        float2 vv[4];
#pragma unroll
        for (int j = 0; j < 4; ++j)
          vv[j] = *(const float2*)(vbase + (size_t)(tt + j) * NKVH * HD + 2 * lane);
#pragma unroll
        for (int h = 0; h < GQ; ++h) {
          const float4 pq = *(const float4*)&p_lds[wave][h][blk4 * 16 + tt];  // uniform broadcast
          o2[h].x = fmaf(pq.x, vv[0].x, o2[h].x);
          o2[h].y = fmaf(pq.x, vv[0].y, o2[h].y);
          o2[h].x = fmaf(pq.y, vv[1].x, o2[h].x);
          o2[h].y = fmaf(pq.y, vv[1].y, o2[h].y);
          o2[h].x = fmaf(pq.z, vv[2].x, o2[h].x);
          o2[h].y = fmaf(pq.z, vv[2].y, o2[h].y);
          o2[h].x = fmaf(pq.w, vv[3].x, o2[h].x);
          o2[h].y = fmaf(pq.w, vv[3].y, o2[h].y);
        }
      }
    }
  }

  // ---- per-wave finalize into LDS ----
#pragma unroll
  for (int h = 0; h < GQ; ++h) {
    const float ls = wave_sum64(lpart[h]);
    if (lane == 0) { wm[wave][h] = m_h[h]; wl[wave][h] = ls; }
    wo[wave][h][2 * lane]     = o2[h].x;
    wo[wave][h][2 * lane + 1] = o2[h].y;
  }
  __syncthreads();

  // ---- cross-wave combine: 256 threads = 4 heads x 64 d-pairs ----
  const int h  = tid >> 6;
  const int dp = tid & 63;
  const float M = fmaxf(fmaxf(wm[0][h], wm[1][h]), fmaxf(wm[2][h], wm[3][h]));  // finite (wave 0 ran)
  float L = 0.f, ox = 0.f, oy = 0.f;
#pragma unroll
  for (int w = 0; w < 4; ++w) {
    const float f = __expf(wm[w][h] - M);  // exp(-inf)=0 for waves with no chunks
    L  += wl[w][h] * f;
    ox += wo[w][h][2 * dp] * f;
    oy += wo[w][h][2 * dp + 1] * f;
  }
  const size_t oidx = (size_t)(midx + h) * HD;
  ws_o[oidx + 2 * dp]     = ox;
  ws_o[oidx + 2 * dp + 1] = oy;
  if (dp == 0) { ws_m[midx + h] = M; ws_l[midx + h] = L; }
}

__global__ void attn_combine_kernel(const float* __restrict__ ws_o,
                                    const float* __restrict__ ws_m,
                                    const float* __restrict__ ws_l,
                                    float* __restrict__ out) {
  const int bh = blockIdx.x;        // 0 .. B*H-1
  const int b  = bh / NH;
  const int hg = bh % NH;
  const int kvh = hg / GQ;
  const int h   = hg % GQ;
  const int d = threadIdx.x;        // 128
  const int base = ((b * NKVH + kvh) * NSPLIT) * GQ + h;

  float M = -INFINITY;
#pragma unroll
  for (int s = 0; s < NSPLIT; ++s) M = fmaxf(M, ws_m[base + s * GQ]);
  float L = 0.f, acc = 0.f;
#pragma unroll
  for (int s = 0; s < NSPLIT; ++s) {
    const float f = __expf(ws_m[base + s * GQ] - M);
    L   += ws_l[base + s * GQ] * f;
    acc += ws_o[(size_t)(base + s * GQ) * HD + d] * f;
  }
  out[(size_t)bh * HD + d] = acc / L;
}

extern "C" void kernel_launch(void* const* d_in, const int* in_sizes, int n_in,
                              void* d_out, int out_size, void* d_ws, size_t ws_size,
                              hipStream_t stream) {
  const float* q       = (const float*)d_in[0];
  const float* kc      = (const float*)d_in[1];
  const float* vc      = (const float*)d_in[2];
  const int*   seqlens = (const int*)d_in[3];
  const int*   btab    = (const int*)d_in[4];
  float* out = (float*)d_out;

  float* ws_o = (float*)d_ws;
  float* ws_m = ws_o + (size_t)NB_B * NKVH * NSPLIT * GQ * HD;
  float* ws_l = ws_m + (size_t)NB_B * NKVH * NSPLIT * GQ;

  dim3 grid1(NSPLIT, NKVH, NB_B);
  attn_split_kernel<<<grid1, 256, 0, stream>>>(q, kc, vc, seqlens, btab, ws_o, ws_m, ws_l);
  attn_combine_kernel<<<NB_B * NH, 128, 0, stream>>>(ws_o, ws_m, ws_l, out);
}